// Round 10
// baseline (166.562 us; speedup 1.0000x reference)
//
#include <hip/hip_runtime.h>
#include <hip/hip_bf16.h>

#define NROWS 2048
#define KDIM  128
#define NCELL 16
#define PORD  10
#define MOMS  12          // padded global stride per (k,cell)
#define NJ_TILES 512
#define NBLK_K3 1024

typedef float f32x4  __attribute__((ext_vector_type(4)));
typedef short bf16x8 __attribute__((ext_vector_type(8)));

__device__ __forceinline__ float fexp2(float x){ return __builtin_amdgcn_exp2f(x); }
__device__ __forceinline__ float flog2(float x){ return __builtin_amdgcn_logf(x); }

// sqrt(1/(2*ln2)): exp2(-((t*CS)^2)) = exp(-t^2/2)
#define CS 0.8493218002880191f

// ws float layout
#define OFF_PART   0            // 32*256 partial col sums
#define OFF_ACCUM  8192         // 256 final col sums
#define OFF_JOINT  8448         // 2048
#define OFF_SLOG   10496        // 2048
#define OFF_NRM    12544        // 2048 row norms (bf16-consistent)
#define OFF_MOM    14592        // 128*16*12 = 24576, layout [(k*16+c)*12+m]
#define OFF_CTR    39168        // 1 uint (pad 4)
#define OFF_XS     39172        // ushort[2048*128]; byte 156688, 16B aligned
#define ZERO_BASE  OFF_JOINT
#define ZERO_LEN   (2048 + 2048 + 2048 + 24576 + 4)   // 30724

__device__ __forceinline__ void col_stats_from(float s, float s2, float& scale, float& shift){
  float m = s * (1.f / NROWS);
  float var = fmaxf((s2 - (float)NROWS * m * m) * (1.f / (NROWS - 1)), 0.f);
  scale = 1.f / (sqrtf(var) + 1e-6f);
  shift = -m * scale;
}

// ---------------- K1: partial col sums + zero accumulators -------------------
__global__ __launch_bounds__(1024) void tc_stats(const float* __restrict__ x,
                                                 float* __restrict__ ws){
  const int t  = threadIdx.x;
  const int k  = t & 127;
  const int rg = t >> 7;
  const int r0 = blockIdx.x * 64;
  {
    int idx = blockIdx.x * 1024 + t;
    if (idx < ZERO_LEN) ws[ZERO_BASE + idx] = 0.f;
  }
  float s = 0.f, s2 = 0.f;
  #pragma unroll
  for (int it = 0; it < 8; ++it){
    float v = x[(size_t)(r0 + it * 8 + rg) * KDIM + k];
    s += v;
    s2 = fmaf(v, v, s2);
  }
  __shared__ float ls[8][128], ls2[8][128];
  ls[rg][k] = s; ls2[rg][k] = s2;
  __syncthreads();
  if (t < 128){
    float a = 0.f, b = 0.f;
    #pragma unroll
    for (int g = 0; g < 8; ++g){ a += ls[g][t]; b += ls2[g][t]; }
    ws[OFF_PART + blockIdx.x * 256 + t]       = a;
    ws[OFF_PART + blockIdx.x * 256 + 128 + t] = b;
  }
}

// ---------------- K2: FGT moments + bf16 pack + row norms --------------------
// grid 2048 = 128 k x 16 row-segs; 128 threads.
__global__ __launch_bounds__(128) void tc_moments(const float* __restrict__ x,
                                                  float* __restrict__ ws){
  const int k   = blockIdx.x >> 4;
  const int seg = blockIdx.x & 15;
  const int t   = threadIdx.x;
  __shared__ float lm[NCELL * PORD];   // 160
  lm[t] = 0.f;
  if (t < 32) lm[128 + t] = 0.f;

  float s = 0.f, s2 = 0.f;
  #pragma unroll
  for (int b = 0; b < 32; ++b){
    s  += ws[OFF_PART + b * 256 + k];
    s2 += ws[OFF_PART + b * 256 + 128 + k];
  }
  if (seg == 0 && t == 0){
    ws[OFF_ACCUM + k]       = s;
    ws[OFF_ACCUM + 128 + k] = s2;
  }
  float scale, shift; col_stats_from(s, s2, scale, shift);
  __syncthreads();

  const int row = seg * 128 + t;
  float y = fmaf(x[(size_t)row * KDIM + k], scale, shift);

  // CS-folded bf16 pack + bf16-consistent norm contribution
  {
    __hip_bfloat16 hb = __float2bfloat16(y * CS);
    unsigned short us = *(unsigned short*)&hb;
    ((unsigned short*)(ws + OFF_XS))[(size_t)row * KDIM + k] = us;
    float ybf = __builtin_bit_cast(float, (unsigned int)us << 16);
    atomicAdd(&ws[OFF_NRM + row], ybf * ybf);
  }

  int c = (int)floorf(y * 2.f + 8.f);
  c = min(max(c, 0), NCELL - 1);
  float u = y - (-3.75f + 0.5f * (float)c);
  float* b10 = &lm[c * PORD];
  atomicAdd(&b10[0], 1.f);
  float pw = u;
  atomicAdd(&b10[1], pw);
  pw *= u; atomicAdd(&b10[2], pw * 0.5f);
  pw *= u; atomicAdd(&b10[3], pw * 1.6666666666e-1f);
  pw *= u; atomicAdd(&b10[4], pw * 4.1666666666e-2f);
  pw *= u; atomicAdd(&b10[5], pw * 8.3333333333e-3f);
  pw *= u; atomicAdd(&b10[6], pw * 1.3888888889e-3f);
  pw *= u; atomicAdd(&b10[7], pw * 1.9841269841e-4f);
  pw *= u; atomicAdd(&b10[8], pw * 2.4801587302e-5f);
  pw *= u; atomicAdd(&b10[9], pw * 2.7557319224e-6f);
  __syncthreads();

  float* mom = ws + OFF_MOM;
  for (int idx = t; idx < NCELL * PORD; idx += 128){
    int c2 = idx / PORD, m = idx - c2 * PORD;
    atomicAdd(&mom[(size_t)(k * NCELL + c2) * MOMS + m], lm[idx]);
  }
}

// ---------------- K3: heterogeneous grid -------------------------------------
// blocks 0..511: no-LDS MFMA Gram tile (bi=bid>>5 -> 128 i-rows, bj=bid&31 -> 64 j-rows)
// blocks 512..1023: FGT marginal eval, 4 rows x 128 k each
__global__ __launch_bounds__(512) void tc_joint(const float* __restrict__ x,
                                                float* __restrict__ ws,
                                                float* __restrict__ out){
  __shared__ float red2[8];
  __shared__ int lastflag;
  const int t = threadIdx.x;
  const int wave = t >> 6, lane = t & 63;
  const int bid = blockIdx.x;
  float* joint = ws + OFF_JOINT;
  float* slog  = ws + OFF_SLOG;
  const float* nrm   = ws + OFF_NRM;
  const float* accum = ws + OFF_ACCUM;
  const float* mom   = ws + OFF_MOM;
  const unsigned short* xs = (const unsigned short*)(ws + OFF_XS);

  if (bid < NJ_TILES){
    const int bi = bid >> 5, bj = bid & 31;
    const int Ibase = bi * 128, Jbase = bj * 64;
    const int wi = wave >> 2, wj = wave & 3;
    const int lr = lane & 15, hs = lane >> 4;

    f32x4 acc0 = {0.f,0.f,0.f,0.f}, acc1 = acc0, acc2 = acc0, acc3 = acc0;
    #pragma unroll
    for (int kq = 0; kq < 4; ++kq){
      const int co = kq * 32 + hs * 8;   // ushort col offset (16B aligned)
      bf16x8 bf = *(const bf16x8*)(xs + (size_t)(Jbase + wj * 16 + lr) * KDIM + co);
      bf16x8 a0 = *(const bf16x8*)(xs + (size_t)(Ibase + wi * 64 + lr +  0) * KDIM + co);
      bf16x8 a1 = *(const bf16x8*)(xs + (size_t)(Ibase + wi * 64 + lr + 16) * KDIM + co);
      bf16x8 a2 = *(const bf16x8*)(xs + (size_t)(Ibase + wi * 64 + lr + 32) * KDIM + co);
      bf16x8 a3 = *(const bf16x8*)(xs + (size_t)(Ibase + wi * 64 + lr + 48) * KDIM + co);
      acc0 = __builtin_amdgcn_mfma_f32_16x16x32_bf16(a0, bf, acc0, 0, 0, 0);
      acc1 = __builtin_amdgcn_mfma_f32_16x16x32_bf16(a1, bf, acc1, 0, 0, 0);
      acc2 = __builtin_amdgcn_mfma_f32_16x16x32_bf16(a2, bf, acc2, 0, 0, 0);
      acc3 = __builtin_amdgcn_mfma_f32_16x16x32_bf16(a3, bf, acc3, 0, 0, 0);
    }

    // epilogue: pd = nI + nJ - 2g; exp2(-pd); reduce over the 16 cols per wave
    const float njv = nrm[Jbase + wj * 16 + lr];
    const int rbase = hs * 4;
    float jp[4][4];
    #pragma unroll
    for (int mt = 0; mt < 4; ++mt){
      f32x4 a4 = (mt == 0) ? acc0 : (mt == 1) ? acc1 : (mt == 2) ? acc2 : acc3;
      const float4 nI4 = *(const float4*)(nrm + Ibase + wi * 64 + mt * 16 + rbase);
      jp[mt][0] = fexp2(-(nI4.x + njv - 2.f * a4[0]));
      jp[mt][1] = fexp2(-(nI4.y + njv - 2.f * a4[1]));
      jp[mt][2] = fexp2(-(nI4.z + njv - 2.f * a4[2]));
      jp[mt][3] = fexp2(-(nI4.w + njv - 2.f * a4[3]));
    }
    #pragma unroll
    for (int mt = 0; mt < 4; ++mt){
      #pragma unroll
      for (int p = 0; p < 4; ++p){
        float v = jp[mt][p];
        v += __shfl_xor(v, 1); v += __shfl_xor(v, 2);
        v += __shfl_xor(v, 4); v += __shfl_xor(v, 8);
        jp[mt][p] = v;
      }
    }
    if (lr == 0){
      #pragma unroll
      for (int mt = 0; mt < 4; ++mt)
        #pragma unroll
        for (int p = 0; p < 4; ++p)
          atomicAdd(&joint[Ibase + wi * 64 + mt * 16 + rbase + p], jp[mt][p]);
    }
  } else {
    // ---- FGT marginal eval: rows (bid-512)*4 .. +3 ----
    const int k  = t & 127;
    const int ir = t >> 7;
    const int r  = (bid - NJ_TILES) * 4 + ir;
    float scale, shift;
    col_stats_from(accum[k], accum[128 + k], scale, shift);
    const float y = fmaf(x[(size_t)r * KDIM + k], scale, shift);
    float S = 0.f;
    #pragma unroll
    for (int c = 0; c < NCELL; ++c){
      const float* mp = mom + (size_t)(k * NCELL + c) * MOMS;
      const float4 v0 = *(const float4*)(mp);
      const float4 v1 = *(const float4*)(mp + 4);
      const float4 v2 = *(const float4*)(mp + 8);
      float sC  = y - (-3.75f + 0.5f * (float)c);
      float scl = sC * CS;
      float e  = fexp2(-(scl * scl));
      float prev = 1.f, cur = sC, nxt;
      float inner = fmaf(v0.y, sC, v0.x);
      nxt = fmaf(sC, cur, -1.f * prev); inner = fmaf(v0.z, nxt, inner); prev = cur; cur = nxt;
      nxt = fmaf(sC, cur, -2.f * prev); inner = fmaf(v0.w, nxt, inner); prev = cur; cur = nxt;
      nxt = fmaf(sC, cur, -3.f * prev); inner = fmaf(v1.x, nxt, inner); prev = cur; cur = nxt;
      nxt = fmaf(sC, cur, -4.f * prev); inner = fmaf(v1.y, nxt, inner); prev = cur; cur = nxt;
      nxt = fmaf(sC, cur, -5.f * prev); inner = fmaf(v1.z, nxt, inner); prev = cur; cur = nxt;
      nxt = fmaf(sC, cur, -6.f * prev); inner = fmaf(v1.w, nxt, inner); prev = cur; cur = nxt;
      nxt = fmaf(sC, cur, -7.f * prev); inner = fmaf(v2.x, nxt, inner); prev = cur; cur = nxt;
      nxt = fmaf(sC, cur, -8.f * prev); inner = fmaf(v2.y, nxt, inner);
      S = fmaf(e, inner, S);
    }
    float lg = flog2(S);
    #pragma unroll
    for (int off = 1; off < 64; off <<= 1) lg += __shfl_xor(lg, off);
    if (lane == 0) atomicAdd(&slog[r], lg);
  }

  // ---- arrival counter; last block finalizes ----
  __syncthreads();
  if (t == 0){
    __threadfence();
    unsigned int* ctr = (unsigned int*)(ws + OFF_CTR);
    unsigned int old = __hip_atomic_fetch_add(ctr, 1u, __ATOMIC_ACQ_REL, __HIP_MEMORY_SCOPE_AGENT);
    lastflag = (old == NBLK_K3 - 1);
  }
  __syncthreads();
  if (lastflag){
    float acc = 0.f;
    #pragma unroll
    for (int q = 0; q < 4; ++q){
      int r = q * 512 + t;
      float jv = __hip_atomic_load(&joint[r], __ATOMIC_RELAXED, __HIP_MEMORY_SCOPE_AGENT);
      float sv = __hip_atomic_load(&slog[r],  __ATOMIC_RELAXED, __HIP_MEMORY_SCOPE_AGENT);
      acc += 0.6931471805599453f * (flog2(jv) - sv);
    }
    #pragma unroll
    for (int m = 1; m < 64; m <<= 1) acc += __shfl_xor(acc, m);
    if (lane == 0) red2[wave] = acc;
    __syncthreads();
    if (t == 0){
      float tot = 0.f;
      #pragma unroll
      for (int w = 0; w < 8; ++w) tot += red2[w];
      out[0] = tot * (1.0f / NROWS) + 968.32661124224364f;  // +127*ln(2048)
    }
  }
}

// ---------------- launch -----------------------------------------------------
extern "C" void kernel_launch(void* const* d_in, const int* in_sizes, int n_in,
                              void* d_out, int out_size, void* d_ws, size_t ws_size,
                              hipStream_t stream){
  const float* x = (const float*)d_in[0];
  float* out = (float*)d_out;
  float* ws  = (float*)d_ws;
  tc_stats  <<<32, 1024, 0, stream>>>(x, ws);
  tc_moments<<<KDIM * 16, 128, 0, stream>>>(x, ws);
  tc_joint  <<<NBLK_K3, 512, 0, stream>>>(x, ws, out);
}

// Round 11
// 136.743 us; speedup vs baseline: 1.2181x; 1.2181x over previous
//
#include <hip/hip_runtime.h>
#include <hip/hip_bf16.h>

#define NROWS 2048
#define KDIM  128
#define NCELL 16
#define PORD  10
#define NGRAM 512
#define NEVAL 256

typedef float f32x4  __attribute__((ext_vector_type(4)));
typedef short bf16x8 __attribute__((ext_vector_type(8)));

__device__ __forceinline__ float fexp2(float x){ return __builtin_amdgcn_exp2f(x); }
__device__ __forceinline__ float flog2(float x){ return __builtin_amdgcn_logf(x); }

// sqrt(1/(2*ln2)): exp2(-((t*CS)^2)) = exp(-t^2/2)
#define CS 0.8493218002880191f

// ws float layout
#define OFF_PART   0            // 32*256 partial col sums
#define OFF_ACCUM  8192         // 256 final col sums
#define OFF_JOINT  8448         // 2048
#define OFF_SLOG   10496        // 2048
#define OFF_NRM    12544        // 2048 row norms (bf16-consistent)
#define OFF_MOM    14592        // [(c*10+m)*128 + k], 16*10*128 = 20480
#define OFF_CTR    35072        // 1 uint
#define OFF_XS     35076        // ushort[2048*128]; byte 140304 (16B aligned)
#define ZERO_BASE  OFF_JOINT
#define ZERO_LEN   (2048 + 2048 + 2048 + 20480 + 4)   // 26628

__device__ __forceinline__ void col_stats_from(float s, float s2, float& scale, float& shift){
  float m = s * (1.f / NROWS);
  float var = fmaxf((s2 - (float)NROWS * m * m) * (1.f / (NROWS - 1)), 0.f);
  scale = 1.f / (sqrtf(var) + 1e-6f);
  shift = -m * scale;
}

// e^{-s^2/2} * sum_m q_m He_m(s)
__device__ __forceinline__ float hermCell(float s,
    float q0, float q1, float q2, float q3, float q4,
    float q5, float q6, float q7, float q8, float q9){
  float scl = s * CS;
  float e = fexp2(-(scl * scl));
  float prev = 1.f, cur = s, nxt;
  float inner = fmaf(q1, s, q0);
  nxt = fmaf(s, cur, -1.f * prev); inner = fmaf(q2, nxt, inner); prev = cur; cur = nxt;
  nxt = fmaf(s, cur, -2.f * prev); inner = fmaf(q3, nxt, inner); prev = cur; cur = nxt;
  nxt = fmaf(s, cur, -3.f * prev); inner = fmaf(q4, nxt, inner); prev = cur; cur = nxt;
  nxt = fmaf(s, cur, -4.f * prev); inner = fmaf(q5, nxt, inner); prev = cur; cur = nxt;
  nxt = fmaf(s, cur, -5.f * prev); inner = fmaf(q6, nxt, inner); prev = cur; cur = nxt;
  nxt = fmaf(s, cur, -6.f * prev); inner = fmaf(q7, nxt, inner); prev = cur; cur = nxt;
  nxt = fmaf(s, cur, -7.f * prev); inner = fmaf(q8, nxt, inner); prev = cur; cur = nxt;
  nxt = fmaf(s, cur, -8.f * prev); inner = fmaf(q9, nxt, inner);
  return e * inner;
}

// ---------------- K1: partial col sums + zero accumulators -------------------
__global__ __launch_bounds__(1024) void tc_stats(const float* __restrict__ x,
                                                 float* __restrict__ ws){
  const int t  = threadIdx.x;
  const int k  = t & 127;
  const int rg = t >> 7;
  const int r0 = blockIdx.x * 64;
  {
    int idx = blockIdx.x * 1024 + t;
    if (idx < ZERO_LEN) ws[ZERO_BASE + idx] = 0.f;
  }
  float s = 0.f, s2 = 0.f;
  #pragma unroll
  for (int it = 0; it < 8; ++it){
    float v = x[(size_t)(r0 + it * 8 + rg) * KDIM + k];
    s += v;
    s2 = fmaf(v, v, s2);
  }
  __shared__ float ls[8][128], ls2[8][128];
  ls[rg][k] = s; ls2[rg][k] = s2;
  __syncthreads();
  if (t < 128){
    float a = 0.f, b = 0.f;
    #pragma unroll
    for (int g = 0; g < 8; ++g){ a += ls[g][t]; b += ls2[g][t]; }
    ws[OFF_PART + blockIdx.x * 256 + t]       = a;
    ws[OFF_PART + blockIdx.x * 256 + 128 + t] = b;
  }
}

// ---------------- K2: FGT moments + bf16 pack + row norms --------------------
// grid 2048 = 128 k x 16 row-segs; 128 threads.
__global__ __launch_bounds__(128) void tc_moments(const float* __restrict__ x,
                                                  float* __restrict__ ws){
  const int k   = blockIdx.x >> 4;
  const int seg = blockIdx.x & 15;
  const int t   = threadIdx.x;
  __shared__ float lm[NCELL * PORD];   // 160
  lm[t] = 0.f;
  if (t < 32) lm[128 + t] = 0.f;

  float s = 0.f, s2 = 0.f;
  #pragma unroll
  for (int b = 0; b < 32; ++b){
    s  += ws[OFF_PART + b * 256 + k];
    s2 += ws[OFF_PART + b * 256 + 128 + k];
  }
  if (seg == 0 && t == 0){
    ws[OFF_ACCUM + k]       = s;
    ws[OFF_ACCUM + 128 + k] = s2;
  }
  float scale, shift; col_stats_from(s, s2, scale, shift);
  __syncthreads();

  const int row = seg * 128 + t;
  float y = fmaf(x[(size_t)row * KDIM + k], scale, shift);

  // CS-folded bf16 pack + bf16-consistent norm contribution
  {
    __hip_bfloat16 hb = __float2bfloat16(y * CS);
    unsigned short us = *(unsigned short*)&hb;
    ((unsigned short*)(ws + OFF_XS))[(size_t)row * KDIM + k] = us;
    float ybf = __builtin_bit_cast(float, (unsigned int)us << 16);
    atomicAdd(&ws[OFF_NRM + row], ybf * ybf);
  }

  int c = (int)floorf(y * 2.f + 8.f);
  c = min(max(c, 0), NCELL - 1);
  float u = y - (-3.75f + 0.5f * (float)c);
  float* b10 = &lm[c * PORD];
  atomicAdd(&b10[0], 1.f);
  float pw = u;
  atomicAdd(&b10[1], pw);
  pw *= u; atomicAdd(&b10[2], pw * 0.5f);
  pw *= u; atomicAdd(&b10[3], pw * 1.6666666666e-1f);
  pw *= u; atomicAdd(&b10[4], pw * 4.1666666666e-2f);
  pw *= u; atomicAdd(&b10[5], pw * 8.3333333333e-3f);
  pw *= u; atomicAdd(&b10[6], pw * 1.3888888889e-3f);
  pw *= u; atomicAdd(&b10[7], pw * 1.9841269841e-4f);
  pw *= u; atomicAdd(&b10[8], pw * 2.4801587302e-5f);
  pw *= u; atomicAdd(&b10[9], pw * 2.7557319224e-6f);
  __syncthreads();

  // transposed moment store: mom[(c*10+m)*128 + k] = mom[idx*128 + k]
  float* mom = ws + OFF_MOM;
  for (int idx = t; idx < NCELL * PORD; idx += 128)
    atomicAdd(&mom[(size_t)idx * KDIM + k], lm[idx]);
}

// ---------------- K3a: no-LDS MFMA Gram joint --------------------------------
// 512 blocks x 512 thr; block = (bi,bj) -> G rows [bi*128,+128) x cols [bj*64,+64)
__global__ __launch_bounds__(512) void tc_gram(float* __restrict__ ws){
  const int t = threadIdx.x;
  const int wave = t >> 6, lane = t & 63;
  const int bid = blockIdx.x;
  const int bi = bid >> 5, bj = bid & 31;
  const int Ibase = bi * 128, Jbase = bj * 64;
  float* joint = ws + OFF_JOINT;
  const float* nrm = ws + OFF_NRM;
  const unsigned short* xs = (const unsigned short*)(ws + OFF_XS);

  const int wi = wave >> 2, wj = wave & 3;
  const int lr = lane & 15, hs = lane >> 4;

  f32x4 acc0 = {0.f,0.f,0.f,0.f}, acc1 = acc0, acc2 = acc0, acc3 = acc0;
  #pragma unroll
  for (int kq = 0; kq < 4; ++kq){
    const int co = kq * 32 + hs * 8;   // ushort col offset (16B aligned)
    bf16x8 bf = *(const bf16x8*)(xs + (size_t)(Jbase + wj * 16 + lr) * KDIM + co);
    bf16x8 a0 = *(const bf16x8*)(xs + (size_t)(Ibase + wi * 64 + lr +  0) * KDIM + co);
    bf16x8 a1 = *(const bf16x8*)(xs + (size_t)(Ibase + wi * 64 + lr + 16) * KDIM + co);
    bf16x8 a2 = *(const bf16x8*)(xs + (size_t)(Ibase + wi * 64 + lr + 32) * KDIM + co);
    bf16x8 a3 = *(const bf16x8*)(xs + (size_t)(Ibase + wi * 64 + lr + 48) * KDIM + co);
    acc0 = __builtin_amdgcn_mfma_f32_16x16x32_bf16(a0, bf, acc0, 0, 0, 0);
    acc1 = __builtin_amdgcn_mfma_f32_16x16x32_bf16(a1, bf, acc1, 0, 0, 0);
    acc2 = __builtin_amdgcn_mfma_f32_16x16x32_bf16(a2, bf, acc2, 0, 0, 0);
    acc3 = __builtin_amdgcn_mfma_f32_16x16x32_bf16(a3, bf, acc3, 0, 0, 0);
  }

  // epilogue: pd = nI + nJ - 2g; exp2(-pd) flushes to 0 for far pairs
  const float njv = nrm[Jbase + wj * 16 + lr];
  const int rbase = hs * 4;
  float jp[4][4];
  #pragma unroll
  for (int mt = 0; mt < 4; ++mt){
    f32x4 a4 = (mt == 0) ? acc0 : (mt == 1) ? acc1 : (mt == 2) ? acc2 : acc3;
    const float4 nI4 = *(const float4*)(nrm + Ibase + wi * 64 + mt * 16 + rbase);
    jp[mt][0] = fexp2(-(nI4.x + njv - 2.f * a4[0]));
    jp[mt][1] = fexp2(-(nI4.y + njv - 2.f * a4[1]));
    jp[mt][2] = fexp2(-(nI4.z + njv - 2.f * a4[2]));
    jp[mt][3] = fexp2(-(nI4.w + njv - 2.f * a4[3]));
  }
  #pragma unroll
  for (int mt = 0; mt < 4; ++mt){
    #pragma unroll
    for (int p = 0; p < 4; ++p){
      float v = jp[mt][p];
      v += __shfl_xor(v, 1); v += __shfl_xor(v, 2);
      v += __shfl_xor(v, 4); v += __shfl_xor(v, 8);
      jp[mt][p] = v;
    }
  }
  if (lr == 0){
    #pragma unroll
    for (int mt = 0; mt < 4; ++mt)
      #pragma unroll
      for (int p = 0; p < 4; ++p)
        atomicAdd(&joint[Ibase + wi * 64 + mt * 16 + rbase + p], jp[mt][p]);
  }
}

// ---------------- K3b: FGT eval (coalesced moments) + finalize ---------------
// 256 blocks x 512 thr; block = 8 rows; thread (k=t&127, irg=t>>7) -> 2 rows.
__global__ __launch_bounds__(512) void tc_eval(const float* __restrict__ x,
                                               float* __restrict__ ws,
                                               float* __restrict__ out){
  __shared__ float red2[8];
  __shared__ int lastflag;
  const int t = threadIdx.x;
  const int wave = t >> 6, lane = t & 63;
  const int k = t & 127, irg = t >> 7;
  const int bid = blockIdx.x;
  const int r0 = bid * 8 + irg * 2;
  float* joint = ws + OFF_JOINT;
  float* slog  = ws + OFF_SLOG;
  const float* accum = ws + OFF_ACCUM;
  const float* mom   = ws + OFF_MOM;

  float scale, shift;
  col_stats_from(accum[k], accum[128 + k], scale, shift);
  const float y0 = fmaf(x[(size_t)r0 * KDIM + k],       scale, shift);
  const float y1 = fmaf(x[(size_t)(r0 + 1) * KDIM + k], scale, shift);

  float S0 = 0.f, S1 = 0.f;
  #pragma unroll
  for (int c = 0; c < NCELL; ++c){
    const float* mp = mom + (size_t)c * PORD * KDIM + k;   // scalar coalesced
    const float q0 = mp[0 * KDIM], q1 = mp[1 * KDIM], q2 = mp[2 * KDIM];
    const float q3 = mp[3 * KDIM], q4 = mp[4 * KDIM], q5 = mp[5 * KDIM];
    const float q6 = mp[6 * KDIM], q7 = mp[7 * KDIM], q8 = mp[8 * KDIM];
    const float q9 = mp[9 * KDIM];
    const float ctr = -3.75f + 0.5f * (float)c;
    S0 += hermCell(y0 - ctr, q0,q1,q2,q3,q4,q5,q6,q7,q8,q9);
    S1 += hermCell(y1 - ctr, q0,q1,q2,q3,q4,q5,q6,q7,q8,q9);
  }
  float lg0 = flog2(S0), lg1 = flog2(S1);
  #pragma unroll
  for (int off = 1; off < 64; off <<= 1){
    lg0 += __shfl_xor(lg0, off);
    lg1 += __shfl_xor(lg1, off);
  }
  if (lane == 0){                      // 2 waves per row-pair (k halves)
    atomicAdd(&slog[r0],     lg0);
    atomicAdd(&slog[r0 + 1], lg1);
  }

  // ---- arrival counter over eval blocks; last finalizes (joint done: stream order)
  __syncthreads();
  if (t == 0){
    __threadfence();
    unsigned int* ctr = (unsigned int*)(ws + OFF_CTR);
    unsigned int old = __hip_atomic_fetch_add(ctr, 1u, __ATOMIC_ACQ_REL, __HIP_MEMORY_SCOPE_AGENT);
    lastflag = (old == NEVAL - 1);
  }
  __syncthreads();
  if (lastflag){
    float acc = 0.f;
    #pragma unroll
    for (int q = 0; q < 4; ++q){
      int r = q * 512 + t;
      float jv = __hip_atomic_load(&joint[r], __ATOMIC_RELAXED, __HIP_MEMORY_SCOPE_AGENT);
      float sv = __hip_atomic_load(&slog[r],  __ATOMIC_RELAXED, __HIP_MEMORY_SCOPE_AGENT);
      acc += 0.6931471805599453f * (flog2(jv) - sv);
    }
    #pragma unroll
    for (int m = 1; m < 64; m <<= 1) acc += __shfl_xor(acc, m);
    if (lane == 0) red2[wave] = acc;
    __syncthreads();
    if (t == 0){
      float tot = 0.f;
      #pragma unroll
      for (int w = 0; w < 8; ++w) tot += red2[w];
      out[0] = tot * (1.0f / NROWS) + 968.32661124224364f;  // +127*ln(2048)
    }
  }
}

// ---------------- launch -----------------------------------------------------
extern "C" void kernel_launch(void* const* d_in, const int* in_sizes, int n_in,
                              void* d_out, int out_size, void* d_ws, size_t ws_size,
                              hipStream_t stream){
  const float* x = (const float*)d_in[0];
  float* out = (float*)d_out;
  float* ws  = (float*)d_ws;
  tc_stats  <<<32, 1024, 0, stream>>>(x, ws);
  tc_moments<<<KDIM * 16, 128, 0, stream>>>(x, ws);
  tc_gram   <<<NGRAM, 512, 0, stream>>>(ws);
  tc_eval   <<<NEVAL, 512, 0, stream>>>(x, ws, out);
}